// Round 1
// baseline (182.012 us; speedup 1.0000x reference)
//
#include <hip/hip_runtime.h>
#include <hip/hip_bf16.h>

// GCN layer: out = segment_sum(edge_val * (x@W)[col], row) + bias
// N=100000 nodes, E=640000 edges, D=128.

#define N_NODES 100000
#define N_EDGES 640000
#define D 128

// ---------------- GEMM: y = x @ W ----------------
// Block: 256 threads, BM=32 rows. K processed in two 64-phases so LDS stays
// at 32KB (W half) + 8KB (x tile) = 40KB -> 4 blocks/CU.
// Thread (tr=tid>>5, tc=tid&31): rows tr*4..tr*4+3, cols tc*4..tc*4+3.
__global__ __launch_bounds__(256) void gemm_xw(const float* __restrict__ x,
                                               const float* __restrict__ w,
                                               float* __restrict__ y) {
    __shared__ float wl[64 * 128];   // W[kphase rows][128]
    __shared__ float xl[32 * 64];    // x[32 rows][64 k]
    const int tid = threadIdx.x;
    const int tc = tid & 31;
    const int tr = tid >> 5;
    const int br = blockIdx.x * 32;

    float acc[4][4] = {};

    for (int kp = 0; kp < 2; ++kp) {
        // stage W half: 64x128 floats = 2048 float4, 8 per thread (coalesced)
        {
            const float4* wg = (const float4*)(w + kp * 64 * 128);
            float4* wl4 = (float4*)wl;
            #pragma unroll
            for (int it = 0; it < 8; ++it)
                wl4[tid + it * 256] = wg[tid + it * 256];
            // stage x tile: 32 rows x 64 k = 512 float4, 2 per thread
            float4* xl4 = (float4*)xl;
            #pragma unroll
            for (int it = 0; it < 2; ++it) {
                int t = tid + it * 256;
                int r = t >> 4, c4 = t & 15;
                xl4[t] = *(const float4*)(x + (size_t)(br + r) * D + kp * 64 + c4 * 4);
            }
        }
        __syncthreads();

        #pragma unroll
        for (int k4 = 0; k4 < 64; k4 += 4) {
            float4 xv[4], wv[4];
            #pragma unroll
            for (int rr = 0; rr < 4; ++rr)
                xv[rr] = *(const float4*)&xl[(tr * 4 + rr) * 64 + k4];
            #pragma unroll
            for (int kk = 0; kk < 4; ++kk)
                wv[kk] = *(const float4*)&wl[(k4 + kk) * 128 + tc * 4];
            #pragma unroll
            for (int rr = 0; rr < 4; ++rr) {
                const float* xs = (const float*)&xv[rr];
                #pragma unroll
                for (int kk = 0; kk < 4; ++kk) {
                    acc[rr][0] += xs[kk] * wv[kk].x;
                    acc[rr][1] += xs[kk] * wv[kk].y;
                    acc[rr][2] += xs[kk] * wv[kk].z;
                    acc[rr][3] += xs[kk] * wv[kk].w;
                }
            }
        }
        __syncthreads();
    }

    #pragma unroll
    for (int rr = 0; rr < 4; ++rr) {
        float4 o = {acc[rr][0], acc[rr][1], acc[rr][2], acc[rr][3]};
        *(float4*)(y + (size_t)(br + tr * 4 + rr) * D + tc * 4) = o;
    }
}

// ---------------- CSR build ----------------
__global__ void histo_rows(const int* __restrict__ row, int* __restrict__ counts) {
    int i = blockIdx.x * 256 + threadIdx.x;
    if (i < N_EDGES) atomicAdd(&counts[row[i]], 1);
}

// per-256-block exclusive scan; blockSums[b] = block total
__global__ void scan_blocks(const int* __restrict__ counts, int* __restrict__ rowStart,
                            int* __restrict__ blockSums) {
    __shared__ int s[256];
    const int tid = threadIdx.x;
    const int i = blockIdx.x * 256 + tid;
    int v = (i < N_NODES) ? counts[i] : 0;
    s[tid] = v;
    __syncthreads();
    for (int off = 1; off < 256; off <<= 1) {
        int t = (tid >= off) ? s[tid - off] : 0;
        __syncthreads();
        s[tid] += t;
        __syncthreads();
    }
    if (i < N_NODES) rowStart[i] = s[tid] - v;  // exclusive
    if (tid == 255) blockSums[blockIdx.x] = s[255];
}

// single-block exclusive scan of the block sums (nb <= 512)
__global__ void scan_sums(int* __restrict__ blockSums, int nb) {
    __shared__ int s[512];
    const int tid = threadIdx.x;
    int v = (tid < nb) ? blockSums[tid] : 0;
    s[tid] = v;
    __syncthreads();
    for (int off = 1; off < 512; off <<= 1) {
        int t = (tid >= off) ? s[tid - off] : 0;
        __syncthreads();
        s[tid] += t;
        __syncthreads();
    }
    if (tid < nb) blockSums[tid] = s[tid] - v;  // exclusive offsets
}

__global__ void add_offsets(int* __restrict__ rowStart, int* __restrict__ cursor,
                            const int* __restrict__ blockOffs) {
    int i = blockIdx.x * 256 + threadIdx.x;
    if (i < N_NODES) {
        int v = rowStart[i] + blockOffs[i >> 8];
        rowStart[i] = v;
        cursor[i] = v;
    }
    if (i == 0) rowStart[N_NODES] = N_EDGES;
}

// scatter edges into row-sorted order; pack (val, col) as float2
__global__ void scatter_edges(const float* __restrict__ ev, const int* __restrict__ row,
                              const int* __restrict__ col, int* __restrict__ cursor,
                              float2* __restrict__ es) {
    int i = blockIdx.x * 256 + threadIdx.x;
    if (i < N_EDGES) {
        int p = atomicAdd(&cursor[row[i]], 1);
        float2 e;
        e.x = ev[i];
        e.y = __int_as_float(col[i]);
        es[p] = e;
    }
}

// ---------------- SpMM gather: out[n] = sum edges + bias ----------------
// 32 lanes per node, 8 nodes per 256-thread block. 100000/8 = 12500 blocks.
__global__ __launch_bounds__(256) void spmm_gather(const float* __restrict__ y,
                                                   const float2* __restrict__ es,
                                                   const int* __restrict__ rowStart,
                                                   const float* __restrict__ bias,
                                                   float* __restrict__ out) {
    const int tid = threadIdx.x;
    const int n = blockIdx.x * 8 + (tid >> 5);
    const int l = tid & 31;
    const int s = rowStart[n];
    const int e = rowStart[n + 1];
    const float* yb = y + l * 4;
    float4 acc = {0.f, 0.f, 0.f, 0.f};
    for (int i = s; i < e; ++i) {
        float2 ec = es[i];
        float v = ec.x;
        int c = __float_as_int(ec.y);
        const float4 yv = *(const float4*)(yb + (size_t)c * D);
        acc.x += v * yv.x;
        acc.y += v * yv.y;
        acc.z += v * yv.z;
        acc.w += v * yv.w;
    }
    const float4 b4 = *(const float4*)(bias + l * 4);
    float4 o = {acc.x + b4.x, acc.y + b4.y, acc.z + b4.z, acc.w + b4.w};
    *(float4*)(out + (size_t)n * D + l * 4) = o;
}

// ---------------- launch ----------------
extern "C" void kernel_launch(void* const* d_in, const int* in_sizes, int n_in,
                              void* d_out, int out_size, void* d_ws, size_t ws_size,
                              hipStream_t stream) {
    const float* x = (const float*)d_in[0];
    const float* w = (const float*)d_in[1];
    const float* bias = (const float*)d_in[2];
    const float* ev = (const float*)d_in[3];
    const int* row = (const int*)d_in[4];
    const int* col = (const int*)d_in[5];
    float* out = (float*)d_out;

    // workspace carve-up (256B aligned)
    size_t off = 0;
    auto carve = [&](size_t bytes) -> void* {
        void* p = (char*)d_ws + off;
        off += (bytes + 255) & ~(size_t)255;
        return p;
    };
    float* y = (float*)carve((size_t)N_NODES * D * sizeof(float));
    int* counts = (int*)carve((size_t)N_NODES * sizeof(int));
    int* rowStart = (int*)carve((size_t)(N_NODES + 1) * sizeof(int));
    int* cursor = (int*)carve((size_t)N_NODES * sizeof(int));
    int* blockSums = (int*)carve(512 * sizeof(int));
    float2* es = (float2*)carve((size_t)N_EDGES * sizeof(float2));

    const int nScanBlocks = (N_NODES + 255) / 256;  // 391

    hipMemsetAsync(counts, 0, (size_t)N_NODES * sizeof(int), stream);

    gemm_xw<<<N_NODES / 32, 256, 0, stream>>>(x, w, y);
    histo_rows<<<(N_EDGES + 255) / 256, 256, 0, stream>>>(row, counts);
    scan_blocks<<<nScanBlocks, 256, 0, stream>>>(counts, rowStart, blockSums);
    scan_sums<<<1, 512, 0, stream>>>(blockSums, nScanBlocks);
    add_offsets<<<nScanBlocks, 256, 0, stream>>>(rowStart, cursor, blockSums);
    scatter_edges<<<(N_EDGES + 255) / 256, 256, 0, stream>>>(ev, row, col, cursor, es);
    spmm_gather<<<N_NODES / 8, 256, 0, stream>>>(y, es, rowStart, bias, out);
}

// Round 2
// 140.659 us; speedup vs baseline: 1.2940x; 1.2940x over previous
//
#include <hip/hip_runtime.h>
#include <hip/hip_bf16.h>

// GCN layer: out = segment_sum(edge_val * (x@W)[col], row) + bias
// N=100000 nodes, E=640000 edges, D=128.
// y = x@W kept in bf16 (halves gather traffic); MFMA bf16 GEMM.

#define N_NODES 100000
#define N_EDGES 640000
#define D 128

typedef __attribute__((ext_vector_type(8))) short short8;
typedef __attribute__((ext_vector_type(4))) float f32x4;

__device__ __forceinline__ ushort f2bf(float f) {
    uint u = __float_as_uint(f);
    u += 0x7fff + ((u >> 16) & 1);   // RNE
    return (ushort)(u >> 16);
}
__device__ __forceinline__ float bflo(uint u) { return __uint_as_float(u << 16); }
__device__ __forceinline__ float bfhi(uint u) { return __uint_as_float(u & 0xffff0000u); }

// ---------------- GEMM: y(bf16) = x @ W via MFMA 16x16x32 ----------------
// 512 blocks x 256 thr (4 waves, 2 blocks/CU). W^T staged in LDS once
// (XOR-swizzled so b128 fragment reads are bank-optimal), then ALL of W held
// as 8 ntiles x 4 ksteps of B-fragments in registers. Each wave grid-strides
// over 16-row tiles; A-fragments load directly from global x (f32 -> bf16 in
// regs). No per-tile __syncthreads. Also zeroes `counts` for the histogram.
__global__ __launch_bounds__(256, 2) void gemm_xw(const float* __restrict__ x,
                                                  const float* __restrict__ w,
                                                  ushort* __restrict__ y,
                                                  int* __restrict__ counts) {
    __shared__ ushort wt[128 * 128];  // W^T, swizzled: idx = n*128 + (k ^ ((n&7)<<3))
    const int tid = threadIdx.x;

    int gz = blockIdx.x * 256 + tid;
    if (gz < N_NODES) counts[gz] = 0;

    // stage W^T: read w[k][n0..n0+3] coalesced float4, scatter bf16 into wt
    #pragma unroll
    for (int it = 0; it < 16; ++it) {
        int idx4 = tid + it * 256;        // 4096 float4 = 128x128
        int k = idx4 >> 5;
        int n0 = (idx4 & 31) * 4;
        float4 v = *(const float4*)(w + (size_t)idx4 * 4);
        float vv[4] = {v.x, v.y, v.z, v.w};
        #pragma unroll
        for (int q = 0; q < 4; ++q) {
            int n = n0 + q;
            wt[n * 128 + (k ^ ((n & 7) << 3))] = f2bf(vv[q]);
        }
    }
    __syncthreads();

    const int lane = tid & 63;
    const int l15 = lane & 15;
    const int h = lane >> 4;

    // B fragments: col n = 16j + l15, k = 32*ks + 8h + [0..7] contiguous
    short8 bfr[8][4];
    #pragma unroll
    for (int j = 0; j < 8; ++j) {
        int n = 16 * j + l15;
        #pragma unroll
        for (int ks = 0; ks < 4; ++ks) {
            int k0 = 32 * ks + 8 * h;
            bfr[j][ks] = *(const short8*)&wt[n * 128 + (k0 ^ ((n & 7) << 3))];
        }
    }

    const int waveGlobal = blockIdx.x * 4 + (tid >> 6);
    const int nWaves = gridDim.x * 4;
    const int nTiles = N_NODES / 16;  // 6250 exactly

    for (int t = waveGlobal; t < nTiles; t += nWaves) {
        const float* xr = x + (size_t)(t * 16 + l15) * D;
        float4 xb[8];
        #pragma unroll
        for (int ks = 0; ks < 4; ++ks) {
            xb[2 * ks]     = *(const float4*)(xr + 32 * ks + 8 * h);
            xb[2 * ks + 1] = *(const float4*)(xr + 32 * ks + 8 * h + 4);
        }
        f32x4 acc[8];
        #pragma unroll
        for (int j = 0; j < 8; ++j) acc[j] = (f32x4){0.f, 0.f, 0.f, 0.f};
        #pragma unroll
        for (int ks = 0; ks < 4; ++ks) {
            const float* p0 = (const float*)&xb[2 * ks];
            const float* p1 = (const float*)&xb[2 * ks + 1];
            short8 a;
            a[0] = f2bf(p0[0]); a[1] = f2bf(p0[1]); a[2] = f2bf(p0[2]); a[3] = f2bf(p0[3]);
            a[4] = f2bf(p1[0]); a[5] = f2bf(p1[1]); a[6] = f2bf(p1[2]); a[7] = f2bf(p1[3]);
            #pragma unroll
            for (int j = 0; j < 8; ++j)
                acc[j] = __builtin_amdgcn_mfma_f32_16x16x32_bf16(a, bfr[j][ks], acc[j], 0, 0, 0);
        }
        // C/D: col = 16j + l15, row = t*16 + 4h + r
        ushort* yt = y + (size_t)(t * 16) * D;
        #pragma unroll
        for (int j = 0; j < 8; ++j) {
            #pragma unroll
            for (int r = 0; r < 4; ++r)
                yt[(4 * h + r) * D + 16 * j + l15] = f2bf(acc[j][r]);
        }
    }
}

// ---------------- CSR build ----------------
__global__ void histo_rows(const int* __restrict__ row, int* __restrict__ counts) {
    int i = blockIdx.x * 256 + threadIdx.x;
    if (i < N_EDGES) atomicAdd(&counts[row[i]], 1);
}

__global__ void scan_blocks(const int* __restrict__ counts, int* __restrict__ rowStart,
                            int* __restrict__ blockSums) {
    __shared__ int s[256];
    const int tid = threadIdx.x;
    const int i = blockIdx.x * 256 + tid;
    int v = (i < N_NODES) ? counts[i] : 0;
    s[tid] = v;
    __syncthreads();
    for (int off = 1; off < 256; off <<= 1) {
        int t = (tid >= off) ? s[tid - off] : 0;
        __syncthreads();
        s[tid] += t;
        __syncthreads();
    }
    if (i < N_NODES) rowStart[i] = s[tid] - v;
    if (tid == 255) blockSums[blockIdx.x] = s[255];
}

__global__ void scan_sums(int* __restrict__ blockSums, int nb) {
    __shared__ int s[512];
    const int tid = threadIdx.x;
    int v = (tid < nb) ? blockSums[tid] : 0;
    s[tid] = v;
    __syncthreads();
    for (int off = 1; off < 512; off <<= 1) {
        int t = (tid >= off) ? s[tid - off] : 0;
        __syncthreads();
        s[tid] += t;
        __syncthreads();
    }
    if (tid < nb) blockSums[tid] = s[tid] - v;
}

__global__ void add_offsets(int* __restrict__ rowStart, int* __restrict__ cursor,
                            const int* __restrict__ blockOffs) {
    int i = blockIdx.x * 256 + threadIdx.x;
    if (i < N_NODES) {
        int v = rowStart[i] + blockOffs[i >> 8];
        rowStart[i] = v;
        cursor[i] = v;
    }
    if (i == 0) rowStart[N_NODES] = N_EDGES;
}

__global__ void scatter_edges(const float* __restrict__ ev, const int* __restrict__ row,
                              const int* __restrict__ col, int* __restrict__ cursor,
                              float2* __restrict__ es) {
    int i = blockIdx.x * 256 + threadIdx.x;
    if (i < N_EDGES) {
        int p = atomicAdd(&cursor[row[i]], 1);
        float2 e;
        e.x = ev[i];
        e.y = __int_as_float(col[i]);
        es[p] = e;
    }
}

// ---------------- SpMM gather (bf16 y): out[n] = sum edges + bias ----------
// 1 node per 64-lane wave; two 32-lane halves take alternate edges (2x unroll
// inside each half), combined at the end with a cross-half shuffle.
__global__ __launch_bounds__(256) void spmm_gather(const ushort* __restrict__ y,
                                                   const float2* __restrict__ es,
                                                   const int* __restrict__ rowStart,
                                                   const float* __restrict__ bias,
                                                   float* __restrict__ out) {
    const int tid = threadIdx.x;
    const int n = blockIdx.x * 4 + (tid >> 6);
    const int lane = tid & 63;
    const int half = lane >> 5;
    const int c = lane & 31;

    const int s = rowStart[n];
    const int end = rowStart[n + 1];

    float a0[4] = {0.f, 0.f, 0.f, 0.f};
    float a1[4] = {0.f, 0.f, 0.f, 0.f};

    int e = s + half;
    for (; e + 2 < end; e += 4) {
        float2 e0 = es[e];
        float2 e1 = es[e + 2];
        const ushort* r0 = y + ((size_t)__float_as_int(e0.y) << 7) + c * 4;
        const ushort* r1 = y + ((size_t)__float_as_int(e1.y) << 7) + c * 4;
        uint2 y0 = *(const uint2*)r0;
        uint2 y1 = *(const uint2*)r1;
        float v0 = e0.x, v1 = e1.x;
        a0[0] += v0 * bflo(y0.x); a0[1] += v0 * bfhi(y0.x);
        a0[2] += v0 * bflo(y0.y); a0[3] += v0 * bfhi(y0.y);
        a1[0] += v1 * bflo(y1.x); a1[1] += v1 * bfhi(y1.x);
        a1[2] += v1 * bflo(y1.y); a1[3] += v1 * bfhi(y1.y);
    }
    for (; e < end; e += 2) {
        float2 e0 = es[e];
        const ushort* r0 = y + ((size_t)__float_as_int(e0.y) << 7) + c * 4;
        uint2 y0 = *(const uint2*)r0;
        float v0 = e0.x;
        a0[0] += v0 * bflo(y0.x); a0[1] += v0 * bfhi(y0.x);
        a0[2] += v0 * bflo(y0.y); a0[3] += v0 * bfhi(y0.y);
    }

    float acc[4];
    #pragma unroll
    for (int i = 0; i < 4; ++i) {
        acc[i] = a0[i] + a1[i];
        acc[i] += __shfl_xor(acc[i], 32);
    }
    if (half == 0) {
        const float4 b4 = *(const float4*)(bias + c * 4);
        float4 o = {acc[0] + b4.x, acc[1] + b4.y, acc[2] + b4.z, acc[3] + b4.w};
        *(float4*)(out + (size_t)n * D + c * 4) = o;
    }
}

// ---------------- launch ----------------
extern "C" void kernel_launch(void* const* d_in, const int* in_sizes, int n_in,
                              void* d_out, int out_size, void* d_ws, size_t ws_size,
                              hipStream_t stream) {
    const float* x = (const float*)d_in[0];
    const float* w = (const float*)d_in[1];
    const float* bias = (const float*)d_in[2];
    const float* ev = (const float*)d_in[3];
    const int* row = (const int*)d_in[4];
    const int* col = (const int*)d_in[5];
    float* out = (float*)d_out;

    size_t off = 0;
    auto carve = [&](size_t bytes) -> void* {
        void* p = (char*)d_ws + off;
        off += (bytes + 255) & ~(size_t)255;
        return p;
    };
    ushort* y = (ushort*)carve((size_t)N_NODES * D * sizeof(ushort));
    int* counts = (int*)carve((size_t)N_NODES * sizeof(int));
    int* rowStart = (int*)carve((size_t)(N_NODES + 1) * sizeof(int));
    int* cursor = (int*)carve((size_t)N_NODES * sizeof(int));
    int* blockSums = (int*)carve(512 * sizeof(int));
    float2* es = (float2*)carve((size_t)N_EDGES * sizeof(float2));

    const int nScanBlocks = (N_NODES + 255) / 256;  // 391

    gemm_xw<<<512, 256, 0, stream>>>(x, w, y, counts);
    histo_rows<<<(N_EDGES + 255) / 256, 256, 0, stream>>>(row, counts);
    scan_blocks<<<nScanBlocks, 256, 0, stream>>>(counts, rowStart, blockSums);
    scan_sums<<<1, 512, 0, stream>>>(blockSums, nScanBlocks);
    add_offsets<<<nScanBlocks, 256, 0, stream>>>(rowStart, cursor, blockSums);
    scatter_edges<<<(N_EDGES + 255) / 256, 256, 0, stream>>>(ev, row, col, cursor, es);
    spmm_gather<<<N_NODES / 4, 256, 0, stream>>>(y, es, rowStart, bias, out);
}

// Round 3
// 92.073 us; speedup vs baseline: 1.9768x; 1.5277x over previous
//
#include <hip/hip_runtime.h>
#include <hip/hip_bf16.h>

// GCN layer: out = segment_sum(edge_val * (x@W)[col], row) + bias
// N=100000 nodes, E=640000 edges, D=128.
// y kept bf16. ELL edge layout (16 slots/row) + tiny atomic overflow path.

#define N_NODES 100000
#define N_EDGES 640000
#define D 128
#define ELL_K 16
#define OVF_CAP 8192

typedef __attribute__((ext_vector_type(8))) short short8;
typedef __attribute__((ext_vector_type(4))) float f32x4;
typedef __attribute__((ext_vector_type(4))) ushort us4;

__device__ __forceinline__ ushort f2bf(float f) {
    uint u = __float_as_uint(f);
    u += 0x7fff + ((u >> 16) & 1);   // RNE
    return (ushort)(u >> 16);
}
__device__ __forceinline__ float bflo(uint u) { return __uint_as_float(u << 16); }
__device__ __forceinline__ float bfhi(uint u) { return __uint_as_float(u & 0xffff0000u); }

// ---------------- GEMM: y(bf16) = x @ W via MFMA 16x16x32 ----------------
// W^T staged in LDS (swizzled), held in regs as 8x4 fragments. Swapped-operand
// mfma: D[channel][node] so each lane owns one node-row -> ushort4 stores.
// Also zeroes counts + ovfCnt for the scatter kernel.
__global__ __launch_bounds__(256, 2) void gemm_xw(const float* __restrict__ x,
                                                  const float* __restrict__ w,
                                                  ushort* __restrict__ y,
                                                  int* __restrict__ counts,
                                                  int* __restrict__ ovfCnt) {
    __shared__ ushort wt[128 * 128];  // W^T swizzled: idx = n*128 + (k ^ ((n&7)<<3))
    const int tid = threadIdx.x;

    int gz = blockIdx.x * 256 + tid;
    if (gz < N_NODES) counts[gz] = 0;
    if (gz == 0) *ovfCnt = 0;

    #pragma unroll
    for (int it = 0; it < 16; ++it) {
        int idx4 = tid + it * 256;        // 4096 float4 = 128x128
        int k = idx4 >> 5;
        int n0 = (idx4 & 31) * 4;
        float4 v = *(const float4*)(w + (size_t)idx4 * 4);
        float vv[4] = {v.x, v.y, v.z, v.w};
        #pragma unroll
        for (int q = 0; q < 4; ++q) {
            int n = n0 + q;
            wt[n * 128 + (k ^ ((n & 7) << 3))] = f2bf(vv[q]);
        }
    }
    __syncthreads();

    const int lane = tid & 63;
    const int l15 = lane & 15;
    const int h = lane >> 4;

    // W^T fragments: channel = 16j + l15, k = 32ks + 8h + [0..7]
    short8 bfr[8][4];
    #pragma unroll
    for (int j = 0; j < 8; ++j) {
        int n = 16 * j + l15;
        #pragma unroll
        for (int ks = 0; ks < 4; ++ks) {
            int k0 = 32 * ks + 8 * h;
            bfr[j][ks] = *(const short8*)&wt[n * 128 + (k0 ^ ((n & 7) << 3))];
        }
    }

    const int waveGlobal = blockIdx.x * 4 + (tid >> 6);
    const int nWaves = gridDim.x * 4;
    const int nTiles = N_NODES / 16;  // 6250

    for (int t = waveGlobal; t < nTiles; t += nWaves) {
        const float* xr = x + (size_t)(t * 16 + l15) * D;
        float4 xb[8];
        #pragma unroll
        for (int ks = 0; ks < 4; ++ks) {
            xb[2 * ks]     = *(const float4*)(xr + 32 * ks + 8 * h);
            xb[2 * ks + 1] = *(const float4*)(xr + 32 * ks + 8 * h + 4);
        }
        f32x4 acc[8];
        #pragma unroll
        for (int j = 0; j < 8; ++j) acc[j] = (f32x4){0.f, 0.f, 0.f, 0.f};
        #pragma unroll
        for (int ks = 0; ks < 4; ++ks) {
            const float* p0 = (const float*)&xb[2 * ks];
            const float* p1 = (const float*)&xb[2 * ks + 1];
            short8 a;
            a[0] = f2bf(p0[0]); a[1] = f2bf(p0[1]); a[2] = f2bf(p0[2]); a[3] = f2bf(p0[3]);
            a[4] = f2bf(p1[0]); a[5] = f2bf(p1[1]); a[6] = f2bf(p1[2]); a[7] = f2bf(p1[3]);
            #pragma unroll
            for (int j = 0; j < 8; ++j)
                acc[j] = __builtin_amdgcn_mfma_f32_16x16x32_bf16(bfr[j][ks], a, acc[j], 0, 0, 0);
        }
        // D[row=channel-sub][col=node]: node = t*16 + l15, channel = 16j + 4h + r
        ushort* yn = y + (size_t)(t * 16 + l15) * D;
        #pragma unroll
        for (int j = 0; j < 8; ++j) {
            us4 o;
            o.x = f2bf(acc[j][0]); o.y = f2bf(acc[j][1]);
            o.z = f2bf(acc[j][2]); o.w = f2bf(acc[j][3]);
            *(us4*)(yn + 16 * j + 4 * h) = o;
        }
    }
}

// ---------------- ELL scatter ----------------
__global__ void scatter_ell(const float* __restrict__ ev, const int* __restrict__ row,
                            const int* __restrict__ col, int* __restrict__ counts,
                            float2* __restrict__ es, int* __restrict__ ovfCnt,
                            int* __restrict__ ovfRow, int* __restrict__ ovfCol,
                            float* __restrict__ ovfVal) {
    int i = blockIdx.x * 256 + threadIdx.x;
    if (i >= N_EDGES) return;
    int r = row[i];
    int p = atomicAdd(&counts[r], 1);
    if (p < ELL_K) {
        float2 e;
        e.x = ev[i];
        e.y = __int_as_float(col[i]);
        es[r * ELL_K + p] = e;
    } else {
        int q = atomicAdd(ovfCnt, 1);
        if (q < OVF_CAP) {
            ovfRow[q] = r;
            ovfCol[q] = col[i];
            ovfVal[q] = ev[i];
        }
    }
}

// ---------------- SpMM: 1 node per wave, 2 nodes sequentially -------------
// Edge slots (128B/row) loaded wave-uniform up-front; y gathers issue 4-deep.
__global__ __launch_bounds__(256) void spmm_ell(const ushort* __restrict__ y,
                                                const float2* __restrict__ es,
                                                const int* __restrict__ counts,
                                                const float* __restrict__ bias,
                                                float* __restrict__ out) {
    const int tid = threadIdx.x;
    const int lane = tid & 63;
    const int wid = blockIdx.x * 4 + (tid >> 6);
    const float2 b2 = *(const float2*)(bias + lane * 2);

    #pragma unroll 1
    for (int rep = 0; rep < 2; ++rep) {
        const int n = __builtin_amdgcn_readfirstlane(wid * 2 + rep);
        int deg = counts[n];
        if (deg > ELL_K) deg = ELL_K;
        const float4* er = (const float4*)(es + (size_t)n * ELL_K);  // 8 float4 = 16 slots

        float ax = 0.f, ay = 0.f;
        #pragma unroll
        for (int g = 0; g < 4; ++g) {
            if (4 * g < deg) {
                float4 sA = er[2 * g];
                float4 sB = er[2 * g + 1];
                int c0 = __float_as_int(sA.y);
                int c1 = (4 * g + 1 < deg) ? __float_as_int(sA.w) : c0;
                int c2 = (4 * g + 2 < deg) ? __float_as_int(sB.y) : c0;
                int c3 = (4 * g + 3 < deg) ? __float_as_int(sB.w) : c0;
                uint u0 = *(const uint*)(y + ((size_t)c0 << 7) + lane * 2);
                uint u1 = *(const uint*)(y + ((size_t)c1 << 7) + lane * 2);
                uint u2 = *(const uint*)(y + ((size_t)c2 << 7) + lane * 2);
                uint u3 = *(const uint*)(y + ((size_t)c3 << 7) + lane * 2);
                float v0 = sA.x;
                float v1 = (4 * g + 1 < deg) ? sA.z : 0.f;
                float v2 = (4 * g + 2 < deg) ? sB.x : 0.f;
                float v3 = (4 * g + 3 < deg) ? sB.z : 0.f;
                ax += v0 * bflo(u0); ay += v0 * bfhi(u0);
                ax += v1 * bflo(u1); ay += v1 * bfhi(u1);
                ax += v2 * bflo(u2); ay += v2 * bfhi(u2);
                ax += v3 * bflo(u3); ay += v3 * bfhi(u3);
            }
        }
        float2 o = {ax + b2.x, ay + b2.y};
        *(float2*)(out + ((size_t)n << 7) + lane * 2) = o;
    }
}

// ---------------- overflow fixup (rare, ~50 edges) ----------------
__global__ void ovf_fix(const ushort* __restrict__ y, const int* __restrict__ ovfRow,
                        const int* __restrict__ ovfCol, const float* __restrict__ ovfVal,
                        const int* __restrict__ ovfCnt, float* __restrict__ out) {
    int nOvf = *ovfCnt;
    if (nOvf > OVF_CAP) nOvf = OVF_CAP;
    int total = nOvf * 32;
    for (int idx = blockIdx.x * 256 + threadIdx.x; idx < total; idx += gridDim.x * 256) {
        int e = idx >> 5;
        int c = idx & 31;
        int r = ovfRow[e];
        int col = ovfCol[e];
        float v = ovfVal[e];
        uint2 u = *(const uint2*)(y + ((size_t)col << 7) + c * 4);
        atomicAdd(&out[(size_t)r * D + c * 4 + 0], v * bflo(u.x));
        atomicAdd(&out[(size_t)r * D + c * 4 + 1], v * bfhi(u.x));
        atomicAdd(&out[(size_t)r * D + c * 4 + 2], v * bflo(u.y));
        atomicAdd(&out[(size_t)r * D + c * 4 + 3], v * bfhi(u.y));
    }
}

// ---------------- launch ----------------
extern "C" void kernel_launch(void* const* d_in, const int* in_sizes, int n_in,
                              void* d_out, int out_size, void* d_ws, size_t ws_size,
                              hipStream_t stream) {
    const float* x = (const float*)d_in[0];
    const float* w = (const float*)d_in[1];
    const float* bias = (const float*)d_in[2];
    const float* ev = (const float*)d_in[3];
    const int* row = (const int*)d_in[4];
    const int* col = (const int*)d_in[5];
    float* out = (float*)d_out;

    size_t off = 0;
    auto carve = [&](size_t bytes) -> void* {
        void* p = (char*)d_ws + off;
        off += (bytes + 255) & ~(size_t)255;
        return p;
    };
    ushort* y = (ushort*)carve((size_t)N_NODES * D * sizeof(ushort));
    int* counts = (int*)carve((size_t)N_NODES * sizeof(int));
    float2* es = (float2*)carve((size_t)N_NODES * ELL_K * sizeof(float2));
    int* ovfCnt = (int*)carve(sizeof(int));
    int* ovfRow = (int*)carve(OVF_CAP * sizeof(int));
    int* ovfCol = (int*)carve(OVF_CAP * sizeof(int));
    float* ovfVal = (float*)carve(OVF_CAP * sizeof(float));

    gemm_xw<<<512, 256, 0, stream>>>(x, w, y, counts, ovfCnt);
    scatter_ell<<<(N_EDGES + 255) / 256, 256, 0, stream>>>(ev, row, col, counts, es,
                                                           ovfCnt, ovfRow, ovfCol, ovfVal);
    spmm_ell<<<N_NODES / 8, 256, 0, stream>>>(y, es, counts, bias, out);
    ovf_fix<<<16, 256, 0, stream>>>(y, ovfRow, ovfCol, ovfVal, ovfCnt, out);
}

// Round 4
// 85.748 us; speedup vs baseline: 2.1226x; 1.0738x over previous
//
#include <hip/hip_runtime.h>
#include <hip/hip_bf16.h>

// GCN layer: out = segment_sum(edge_val * (x@W)[col], row) + bias
// N=100000 nodes, E=640000 edges, D=128.
// y bf16. Edge pipeline: 2-level partition (bucket of 256 rows) -> LDS-built
// ELL (16 slots/row) -> wave-per-node gather. Overflow via tiny atomic list.

#define N_NODES 100000
#define N_EDGES 640000
#define D 128
#define ELL_K 16
#define OVF_CAP 8192
#define NB 391          // ceil(N_NODES/256) row buckets
#define BCAP 2048       // per-bucket edge capacity (avg 1638, +10 sigma)
#define CHUNK 4096
#define NCHUNKS 157     // ceil(N_EDGES/CHUNK)

typedef __attribute__((ext_vector_type(8))) short short8;
typedef __attribute__((ext_vector_type(4))) float f32x4;
typedef __attribute__((ext_vector_type(4))) ushort us4;

__device__ __forceinline__ ushort f2bf(float f) {
    uint u = __float_as_uint(f);
    u += 0x7fff + ((u >> 16) & 1);   // RNE
    return (ushort)(u >> 16);
}
__device__ __forceinline__ float bflo(uint u) { return __uint_as_float(u << 16); }
__device__ __forceinline__ float bfhi(uint u) { return __uint_as_float(u & 0xffff0000u); }

// ---------------- GEMM: y(bf16) = x @ W via MFMA 16x16x32 ----------------
// W^T staged in LDS (swizzled), held in regs as 8x4 fragments. Swapped-operand
// mfma: D[channel][node] so each lane owns one node-row -> ushort4 stores.
// Also inits bucketCursor + ovfCnt for the partition kernel.
__global__ __launch_bounds__(256, 2) void gemm_xw(const float* __restrict__ x,
                                                  const float* __restrict__ w,
                                                  ushort* __restrict__ y,
                                                  int* __restrict__ bucketCursor,
                                                  int* __restrict__ ovfCnt) {
    __shared__ ushort wt[128 * 128];  // W^T swizzled: idx = n*128 + (k ^ ((n&7)<<3))
    const int tid = threadIdx.x;

    int gz = blockIdx.x * 256 + tid;
    if (gz < NB) bucketCursor[gz] = gz * BCAP;
    if (gz == 0) *ovfCnt = 0;

    #pragma unroll
    for (int it = 0; it < 16; ++it) {
        int idx4 = tid + it * 256;        // 4096 float4 = 128x128
        int k = idx4 >> 5;
        int n0 = (idx4 & 31) * 4;
        float4 v = *(const float4*)(w + (size_t)idx4 * 4);
        float vv[4] = {v.x, v.y, v.z, v.w};
        #pragma unroll
        for (int q = 0; q < 4; ++q) {
            int n = n0 + q;
            wt[n * 128 + (k ^ ((n & 7) << 3))] = f2bf(vv[q]);
        }
    }
    __syncthreads();

    const int lane = tid & 63;
    const int l15 = lane & 15;
    const int h = lane >> 4;

    // W^T fragments: channel = 16j + l15, k = 32ks + 8h + [0..7]
    short8 bfr[8][4];
    #pragma unroll
    for (int j = 0; j < 8; ++j) {
        int n = 16 * j + l15;
        #pragma unroll
        for (int ks = 0; ks < 4; ++ks) {
            int k0 = 32 * ks + 8 * h;
            bfr[j][ks] = *(const short8*)&wt[n * 128 + (k0 ^ ((n & 7) << 3))];
        }
    }

    const int waveGlobal = blockIdx.x * 4 + (tid >> 6);
    const int nWaves = gridDim.x * 4;
    const int nTiles = N_NODES / 16;  // 6250

    for (int t = waveGlobal; t < nTiles; t += nWaves) {
        const float* xr = x + (size_t)(t * 16 + l15) * D;
        float4 xb[8];
        #pragma unroll
        for (int ks = 0; ks < 4; ++ks) {
            xb[2 * ks]     = *(const float4*)(xr + 32 * ks + 8 * h);
            xb[2 * ks + 1] = *(const float4*)(xr + 32 * ks + 8 * h + 4);
        }
        f32x4 acc[8];
        #pragma unroll
        for (int j = 0; j < 8; ++j) acc[j] = (f32x4){0.f, 0.f, 0.f, 0.f};
        #pragma unroll
        for (int ks = 0; ks < 4; ++ks) {
            const float* p0 = (const float*)&xb[2 * ks];
            const float* p1 = (const float*)&xb[2 * ks + 1];
            short8 a;
            a[0] = f2bf(p0[0]); a[1] = f2bf(p0[1]); a[2] = f2bf(p0[2]); a[3] = f2bf(p0[3]);
            a[4] = f2bf(p1[0]); a[5] = f2bf(p1[1]); a[6] = f2bf(p1[2]); a[7] = f2bf(p1[3]);
            #pragma unroll
            for (int j = 0; j < 8; ++j)
                acc[j] = __builtin_amdgcn_mfma_f32_16x16x32_bf16(bfr[j][ks], a, acc[j], 0, 0, 0);
        }
        // D: node = t*16 + l15, channel = 16j + 4h + r
        ushort* yn = y + (size_t)(t * 16 + l15) * D;
        #pragma unroll
        for (int j = 0; j < 8; ++j) {
            us4 o;
            o.x = f2bf(acc[j][0]); o.y = f2bf(acc[j][1]);
            o.z = f2bf(acc[j][2]); o.w = f2bf(acc[j][3]);
            *(us4*)(yn + 16 * j + 4 * h) = o;
        }
    }
}

// ---------------- partition: edges -> 256-row buckets ----------------
// Per 4096-edge chunk: LDS histogram, one global atomicAdd per bucket to
// reserve a contiguous run, then LDS-cursor scatter of packed 8B records.
// Packed: .x = ev bits, .y = col | (row&255)<<20.
__global__ __launch_bounds__(256) void partition_edges(const float* __restrict__ ev,
                                                       const int* __restrict__ row,
                                                       const int* __restrict__ col,
                                                       int* __restrict__ bucketCursor,
                                                       uint2* __restrict__ es0,
                                                       int* __restrict__ ovfCnt,
                                                       int* __restrict__ ovfRow,
                                                       int* __restrict__ ovfCol,
                                                       float* __restrict__ ovfVal) {
    __shared__ int hist[NB];
    __shared__ int cur[NB];
    const int tid = threadIdx.x;
    const int base = blockIdx.x * CHUNK;

    for (int t = tid; t < NB; t += 256) hist[t] = 0;
    __syncthreads();

    #pragma unroll
    for (int it = 0; it < CHUNK / 256; ++it) {
        int i = base + it * 256 + tid;
        if (i < N_EDGES) atomicAdd(&hist[row[i] >> 8], 1);
    }
    __syncthreads();

    for (int t = tid; t < NB; t += 256) {
        int hcnt = hist[t];
        cur[t] = (hcnt > 0) ? atomicAdd(&bucketCursor[t], hcnt) : 0;
    }
    __syncthreads();

    #pragma unroll
    for (int it = 0; it < CHUNK / 256; ++it) {
        int i = base + it * 256 + tid;
        if (i < N_EDGES) {
            int r = row[i];
            int b = r >> 8;
            int p = atomicAdd(&cur[b], 1);
            if (p < (b + 1) * BCAP) {
                uint2 e;
                e.x = __float_as_uint(ev[i]);
                e.y = (uint)col[i] | ((uint)(r & 255) << 20);
                es0[p] = e;
            } else {
                int q = atomicAdd(ovfCnt, 1);
                if (q < OVF_CAP) {
                    ovfRow[q] = r;
                    ovfCol[q] = col[i];
                    ovfVal[q] = ev[i];
                }
            }
        }
    }
}

// ---------------- build ELL in LDS, write coalesced ----------------
__global__ __launch_bounds__(256) void build_ell(const uint2* __restrict__ es0,
                                                 const int* __restrict__ bucketCursor,
                                                 float2* __restrict__ es,
                                                 int* __restrict__ counts,
                                                 int* __restrict__ ovfCnt,
                                                 int* __restrict__ ovfRow,
                                                 int* __restrict__ ovfCol,
                                                 float* __restrict__ ovfVal) {
    __shared__ float2 ell[256 * ELL_K];   // 32KB
    __shared__ int lcnt[256];
    const int tid = threadIdx.x;
    const int b = blockIdx.x;

    lcnt[tid] = 0;
    __syncthreads();

    int cnt = bucketCursor[b] - b * BCAP;
    if (cnt > BCAP) cnt = BCAP;
    const uint2* src = es0 + (size_t)b * BCAP;

    for (int i = tid; i < cnt; i += 256) {
        uint2 e = src[i];
        int r = e.y >> 20;
        int p = atomicAdd(&lcnt[r], 1);
        if (p < ELL_K) {
            float2 rec;
            rec.x = __uint_as_float(e.x);
            rec.y = __uint_as_float(e.y & 0xFFFFFu);
            ell[r * ELL_K + p] = rec;
        } else {
            int q = atomicAdd(ovfCnt, 1);
            if (q < OVF_CAP) {
                ovfRow[q] = b * 256 + r;
                ovfCol[q] = (int)(e.y & 0xFFFFFu);
                ovfVal[q] = __uint_as_float(e.x);
            }
        }
    }
    __syncthreads();

    const int nbase = b * 256;
    int nvalid = N_NODES - nbase;
    if (nvalid > 256) nvalid = 256;

    if (tid < nvalid) counts[nbase + tid] = lcnt[tid];

    float4* dst4 = (float4*)(es + (size_t)nbase * ELL_K);
    const float4* ell4 = (const float4*)ell;
    for (int t = tid; t < nvalid * (ELL_K / 2); t += 256)
        dst4[t] = ell4[t];
}

// ---------------- SpMM: 1 node per wave, 2 nodes sequentially -------------
__global__ __launch_bounds__(256) void spmm_ell(const ushort* __restrict__ y,
                                                const float2* __restrict__ es,
                                                const int* __restrict__ counts,
                                                const float* __restrict__ bias,
                                                float* __restrict__ out) {
    const int tid = threadIdx.x;
    const int lane = tid & 63;
    const int wid = blockIdx.x * 4 + (tid >> 6);
    const float2 b2 = *(const float2*)(bias + lane * 2);

    #pragma unroll 1
    for (int rep = 0; rep < 2; ++rep) {
        const int n = __builtin_amdgcn_readfirstlane(wid * 2 + rep);
        int deg = counts[n];
        if (deg > ELL_K) deg = ELL_K;
        const float4* er = (const float4*)(es + (size_t)n * ELL_K);  // 8 float4

        float ax = 0.f, ay = 0.f;
        #pragma unroll
        for (int g = 0; g < 4; ++g) {
            if (4 * g < deg) {
                float4 sA = er[2 * g];
                float4 sB = er[2 * g + 1];
                int c0 = __float_as_int(sA.y);
                int c1 = (4 * g + 1 < deg) ? __float_as_int(sA.w) : c0;
                int c2 = (4 * g + 2 < deg) ? __float_as_int(sB.y) : c0;
                int c3 = (4 * g + 3 < deg) ? __float_as_int(sB.w) : c0;
                uint u0 = *(const uint*)(y + ((size_t)c0 << 7) + lane * 2);
                uint u1 = *(const uint*)(y + ((size_t)c1 << 7) + lane * 2);
                uint u2 = *(const uint*)(y + ((size_t)c2 << 7) + lane * 2);
                uint u3 = *(const uint*)(y + ((size_t)c3 << 7) + lane * 2);
                float v0 = sA.x;
                float v1 = (4 * g + 1 < deg) ? sA.z : 0.f;
                float v2 = (4 * g + 2 < deg) ? sB.x : 0.f;
                float v3 = (4 * g + 3 < deg) ? sB.z : 0.f;
                ax += v0 * bflo(u0); ay += v0 * bfhi(u0);
                ax += v1 * bflo(u1); ay += v1 * bfhi(u1);
                ax += v2 * bflo(u2); ay += v2 * bfhi(u2);
                ax += v3 * bflo(u3); ay += v3 * bfhi(u3);
            }
        }
        float2 o = {ax + b2.x, ay + b2.y};
        *(float2*)(out + ((size_t)n << 7) + lane * 2) = o;
    }
}

// ---------------- overflow fixup (rare) ----------------
__global__ void ovf_fix(const ushort* __restrict__ y, const int* __restrict__ ovfRow,
                        const int* __restrict__ ovfCol, const float* __restrict__ ovfVal,
                        const int* __restrict__ ovfCnt, float* __restrict__ out) {
    int nOvf = *ovfCnt;
    if (nOvf > OVF_CAP) nOvf = OVF_CAP;
    int total = nOvf * 32;
    for (int idx = blockIdx.x * 256 + threadIdx.x; idx < total; idx += gridDim.x * 256) {
        int e = idx >> 5;
        int c = idx & 31;
        int r = ovfRow[e];
        int col = ovfCol[e];
        float v = ovfVal[e];
        uint2 u = *(const uint2*)(y + ((size_t)col << 7) + c * 4);
        atomicAdd(&out[(size_t)r * D + c * 4 + 0], v * bflo(u.x));
        atomicAdd(&out[(size_t)r * D + c * 4 + 1], v * bfhi(u.x));
        atomicAdd(&out[(size_t)r * D + c * 4 + 2], v * bflo(u.y));
        atomicAdd(&out[(size_t)r * D + c * 4 + 3], v * bfhi(u.y));
    }
}

// ---------------- launch ----------------
extern "C" void kernel_launch(void* const* d_in, const int* in_sizes, int n_in,
                              void* d_out, int out_size, void* d_ws, size_t ws_size,
                              hipStream_t stream) {
    const float* x = (const float*)d_in[0];
    const float* w = (const float*)d_in[1];
    const float* bias = (const float*)d_in[2];
    const float* ev = (const float*)d_in[3];
    const int* row = (const int*)d_in[4];
    const int* col = (const int*)d_in[5];
    float* out = (float*)d_out;

    size_t off = 0;
    auto carve = [&](size_t bytes) -> void* {
        void* p = (char*)d_ws + off;
        off += (bytes + 255) & ~(size_t)255;
        return p;
    };
    ushort* y = (ushort*)carve((size_t)N_NODES * D * sizeof(ushort));
    int* counts = (int*)carve((size_t)N_NODES * sizeof(int));
    float2* es = (float2*)carve((size_t)N_NODES * ELL_K * sizeof(float2));
    uint2* es0 = (uint2*)carve((size_t)NB * BCAP * sizeof(uint2));
    int* bucketCursor = (int*)carve(NB * sizeof(int));
    int* ovfCnt = (int*)carve(sizeof(int));
    int* ovfRow = (int*)carve(OVF_CAP * sizeof(int));
    int* ovfCol = (int*)carve(OVF_CAP * sizeof(int));
    float* ovfVal = (float*)carve(OVF_CAP * sizeof(float));

    gemm_xw<<<512, 256, 0, stream>>>(x, w, y, bucketCursor, ovfCnt);
    partition_edges<<<NCHUNKS, 256, 0, stream>>>(ev, row, col, bucketCursor, es0,
                                                 ovfCnt, ovfRow, ovfCol, ovfVal);
    build_ell<<<NB, 256, 0, stream>>>(es0, bucketCursor, es, counts,
                                      ovfCnt, ovfRow, ovfCol, ovfVal);
    spmm_ell<<<N_NODES / 8, 256, 0, stream>>>(y, es, counts, bias, out);
    ovf_fix<<<16, 256, 0, stream>>>(y, ovfRow, ovfCol, ovfVal, ovfCnt, out);
}